// Round 1
// baseline (775.497 us; speedup 1.0000x reference)
//
#include <hip/hip_runtime.h>

#define HID 128
#define NR  16

__device__ __forceinline__ float dot4f(float4 a, float4 b) {
    return a.x * b.x + a.y * b.y + a.z * b.z + a.w * b.w;
}

// ---------------- Kernel A: edge gate + scatter-add ----------------
// grid: ceil(E/256) blocks of 256 threads. Each block stages 256 edges'
// distance rows (16 f32 each) + target indices into LDS; each of the 4
// waves processes 64 edges; lane l covers hidden channels 2l, 2l+1.
__global__ __launch_bounds__(256) void edge_kernel(
    const float* __restrict__ dist, const float* __restrict__ msg,
    const int* __restrict__ eidx, const float* __restrict__ Wd,
    float* __restrict__ node_emb, int E)
{
    __shared__ float s_dist[256 * NR];
    __shared__ int   s_tgt[256];

    const int tid  = threadIdx.x;
    const int lane = tid & 63;
    const int wv   = tid >> 6;           // wave id 0..3
    const int e0   = blockIdx.x * 256;

    // Preload Wd rows for h = 2*lane, 2*lane+1 into registers (16 floats each)
    float4 wd[2][4];
#pragma unroll
    for (int j = 0; j < 2; ++j)
#pragma unroll
        for (int q = 0; q < 4; ++q)
            wd[j][q] = *(const float4*)(Wd + (size_t)(2 * lane + j) * NR + q * 4);

    // Stage dist rows (coalesced float4) and target indices
    for (int i = tid; i < 256 * NR / 4; i += 256) {   // 1024 float4s
        int le = i >> 2;
        float4 v = make_float4(0.f, 0.f, 0.f, 0.f);
        if (e0 + le < E) v = *(const float4*)(dist + (size_t)e0 * NR + i * 4);
        *(float4*)(s_dist + i * 4) = v;
    }
    if (e0 + tid < E) s_tgt[tid] = eidx[E + e0 + tid];
    else              s_tgt[tid] = 0;
    __syncthreads();

    int cnt = E - e0 - wv * 64;
    if (cnt > 64) cnt = 64;
    const float4* sd4 = (const float4*)s_dist;

    for (int li = 0; li < cnt; ++li) {
        const int le = wv * 64 + li;
        const int e  = e0 + le;
        // broadcast LDS reads (same address across wave -> free)
        float4 d0 = sd4[le * 4 + 0];
        float4 d1 = sd4[le * 4 + 1];
        float4 d2 = sd4[le * 4 + 2];
        float4 d3 = sd4[le * 4 + 3];
        int tgt = s_tgt[le];
        float2 m = *(const float2*)(msg + (size_t)e * HID + 2 * lane);
        float g0 = dot4f(d0, wd[0][0]) + dot4f(d1, wd[0][1]) +
                   dot4f(d2, wd[0][2]) + dot4f(d3, wd[0][3]);
        float g1 = dot4f(d0, wd[1][0]) + dot4f(d1, wd[1][1]) +
                   dot4f(d2, wd[1][2]) + dot4f(d3, wd[1][3]);
        float* dst = node_emb + (size_t)tgt * HID + 2 * lane;
        unsafeAtomicAdd(dst,     g0 * m.x);
        unsafeAtomicAdd(dst + 1, g1 * m.y);
    }
}

// ---------------- Kernel B: fused 3x(Linear+SiLU) + Linear out ----------------
// grid: ceil(N/64) blocks of 512 threads. 64-node x 128-feature tile lives in
// LDS (row stride 132 floats -> only 2-way bank aliasing, free). Thread tile:
// 4 nodes x 4 hidden. Weights (64 KB/layer) stream through L1.
__global__ __launch_bounds__(512) void node_kernel(
    const float* __restrict__ node_emb, const float* __restrict__ Ws,
    const float* __restrict__ bs, const float* __restrict__ Wout,
    float* __restrict__ out, int N)
{
    __shared__ float xa[64][132];

    const int tid = threadIdx.x;
    const int nb  = blockIdx.x * 64;
    const int hq  = tid & 31, h0 = hq * 4;
    const int nq  = tid >> 5, n0 = nq * 4;

    // load node tile (zero-fill tail)
    for (int i = tid; i < 64 * 32; i += 512) {
        int n = i >> 5, kq = i & 31;
        float4 v = make_float4(0.f, 0.f, 0.f, 0.f);
        if (nb + n < N) v = *(const float4*)(node_emb + (size_t)(nb + n) * HID + kq * 4);
        *(float4*)(&xa[n][kq * 4]) = v;
    }
    __syncthreads();

    for (int l = 0; l < 4; ++l) {
        const float* __restrict__ W = (l < 3) ? (Ws + (size_t)l * HID * HID) : Wout;
        float acc[4][4];
        if (l < 3) {
            float b[4];
#pragma unroll
            for (int j = 0; j < 4; ++j) b[j] = bs[l * HID + h0 + j];
#pragma unroll
            for (int i = 0; i < 4; ++i)
#pragma unroll
                for (int j = 0; j < 4; ++j) acc[i][j] = b[j];
        } else {
#pragma unroll
            for (int i = 0; i < 4; ++i)
#pragma unroll
                for (int j = 0; j < 4; ++j) acc[i][j] = 0.f;
        }

        for (int k4 = 0; k4 < 32; ++k4) {
            float4 xv[4], wvv[4];
#pragma unroll
            for (int i = 0; i < 4; ++i) xv[i] = *(const float4*)(&xa[n0 + i][k4 * 4]);
#pragma unroll
            for (int j = 0; j < 4; ++j) wvv[j] = *(const float4*)(W + (size_t)(h0 + j) * HID + k4 * 4);
#pragma unroll
            for (int i = 0; i < 4; ++i)
#pragma unroll
                for (int j = 0; j < 4; ++j) acc[i][j] += dot4f(xv[i], wvv[j]);
        }
        __syncthreads();   // all reads of xa done

        if (l < 3) {
#pragma unroll
            for (int i = 0; i < 4; ++i) {
                float4 y;
                y.x = acc[i][0] / (1.f + __expf(-acc[i][0]));
                y.y = acc[i][1] / (1.f + __expf(-acc[i][1]));
                y.z = acc[i][2] / (1.f + __expf(-acc[i][2]));
                y.w = acc[i][3] / (1.f + __expf(-acc[i][3]));
                *(float4*)(&xa[n0 + i][h0]) = y;
            }
            __syncthreads();   // writes visible before next layer's reads
        } else {
#pragma unroll
            for (int i = 0; i < 4; ++i) {
                if (nb + n0 + i < N) {
                    float4 y = make_float4(acc[i][0], acc[i][1], acc[i][2], acc[i][3]);
                    *(float4*)(out + (size_t)(nb + n0 + i) * HID + h0) = y;
                }
            }
        }
    }
}

extern "C" void kernel_launch(void* const* d_in, const int* in_sizes, int n_in,
                              void* d_out, int out_size, void* d_ws, size_t ws_size,
                              hipStream_t stream) {
    const float* dist = (const float*)d_in[0];
    const float* msg  = (const float*)d_in[1];
    const int*   eidx = (const int*)d_in[2];
    // d_in[3] = num_nodes (derive N from out_size instead)
    const float* Wd   = (const float*)d_in[4];
    const float* Ws   = (const float*)d_in[5];
    const float* bs   = (const float*)d_in[6];
    const float* Wout = (const float*)d_in[7];
    float* out = (float*)d_out;

    const int E = in_sizes[1] / HID;
    const int N = out_size / HID;

    float* node_emb = (float*)d_ws;
    // ws/out are poisoned 0xAA and not re-poisoned between replays:
    // zero the accumulator every launch (graph-capturable memset).
    hipMemsetAsync(node_emb, 0, (size_t)N * HID * sizeof(float), stream);

    edge_kernel<<<(E + 255) / 256, 256, 0, stream>>>(dist, msg, eidx, Wd, node_emb, E);
    node_kernel<<<(N + 63) / 64, 512, 0, stream>>>(node_emb, Ws, bs, Wout, out, N);
}

// Round 2
// 452.678 us; speedup vs baseline: 1.7131x; 1.7131x over previous
//
#include <hip/hip_runtime.h>

#define HID 128
#define NR  16
#define NLAYER 4   // 3 hidden layers + output layer (transposed together)

__device__ __forceinline__ float dot4f(float4 a, float4 b) {
    return a.x * b.x + a.y * b.y + a.z * b.z + a.w * b.w;
}

// ---- K1: histogram of target indices ----
__global__ void hist_kernel(const int* __restrict__ eidx, int* __restrict__ hist, int E) {
    int e = blockIdx.x * blockDim.x + threadIdx.x;
    if (e < E) atomicAdd(&hist[eidx[E + e]], 1);
}

// ---- K2: single-block exclusive scan over N bins -> offs, curs ----
__global__ __launch_bounds__(1024) void scan_kernel(const int* __restrict__ hist,
                                                    int* __restrict__ offs,
                                                    int* __restrict__ curs, int N) {
    __shared__ int part[1024];
    const int tid = threadIdx.x;
    const int per = (N + 1023) >> 10;
    const int base = tid * per;
    int s = 0;
    for (int i = 0; i < per; ++i) {
        int idx = base + i;
        if (idx < N) s += hist[idx];
    }
    part[tid] = s;
    __syncthreads();
    for (int off = 1; off < 1024; off <<= 1) {
        int v = part[tid];
        int add = (tid >= off) ? part[tid - off] : 0;
        __syncthreads();
        part[tid] = v + add;
        __syncthreads();
    }
    int run = (tid > 0) ? part[tid - 1] : 0;
    for (int i = 0; i < per; ++i) {
        int idx = base + i;
        if (idx < N) {
            offs[idx] = run;
            curs[idx] = run;
            run += hist[idx];
        }
    }
}

// ---- K3: scatter edge ids into per-node contiguous segments ----
__global__ void scatter_kernel(const int* __restrict__ eidx, int* __restrict__ curs,
                               int* __restrict__ sorted, int E) {
    int e = blockIdx.x * blockDim.x + threadIdx.x;
    if (e < E) {
        int t = eidx[E + e];
        int pos = atomicAdd(&curs[t], 1);
        sorted[pos] = e;
    }
}

// ---- K4: transpose weights: WT[l][k][h] = W_l[h][k] (layer 3 = Wout) ----
__global__ void transpose_kernel(const float* __restrict__ Ws, const float* __restrict__ Wout,
                                 float* __restrict__ WT) {
    int i = blockIdx.x * blockDim.x + threadIdx.x;
    if (i >= NLAYER * HID * HID) return;
    int l = i >> 14;
    int rem = i & 16383;
    int h = rem >> 7, k = rem & 127;
    const float* src = (l < 3) ? (Ws + ((size_t)l << 14)) : Wout;
    WT[((size_t)l << 14) + (size_t)k * HID + h] = src[(size_t)h * HID + k];
}

// ---- K5: gather-reduce. One wave per node; lane covers channels 2l, 2l+1 ----
__global__ __launch_bounds__(256) void gather_kernel(
    const float* __restrict__ dist, const float* __restrict__ msg,
    const float* __restrict__ Wd, const int* __restrict__ sorted,
    const int* __restrict__ offs, const int* __restrict__ hist,
    float* __restrict__ node_emb, int N)
{
    const int tid  = threadIdx.x;
    const int lane = tid & 63;
    const int node = blockIdx.x * 4 + (tid >> 6);
    if (node >= N) return;

    // Wd rows for channels 2*lane, 2*lane+1 (16 floats each) in registers
    float4 wd0[4], wd1[4];
#pragma unroll
    for (int q = 0; q < 4; ++q) {
        wd0[q] = *(const float4*)(Wd + (size_t)(2 * lane)     * NR + q * 4);
        wd1[q] = *(const float4*)(Wd + (size_t)(2 * lane + 1) * NR + q * 4);
    }

    const int start = offs[node];
    const int deg   = hist[node];
    float a0 = 0.f, a1 = 0.f;

    for (int i = 0; i < deg; ++i) {
        int e = sorted[start + i];                       // wave-uniform broadcast
        const float4* dr = (const float4*)(dist + (size_t)e * NR);
        float4 d0 = dr[0], d1 = dr[1], d2 = dr[2], d3 = dr[3];   // 64 B broadcast
        float2 m  = *(const float2*)(msg + (size_t)e * HID + 2 * lane); // coalesced
        float g0 = dot4f(d0, wd0[0]) + dot4f(d1, wd0[1]) +
                   dot4f(d2, wd0[2]) + dot4f(d3, wd0[3]);
        float g1 = dot4f(d0, wd1[0]) + dot4f(d1, wd1[1]) +
                   dot4f(d2, wd1[2]) + dot4f(d3, wd1[3]);
        a0 += g0 * m.x;
        a1 += g1 * m.y;
    }
    *(float2*)(node_emb + (size_t)node * HID + 2 * lane) = make_float2(a0, a1);
}

// ---- K6: fused 3x(Linear+SiLU) + Linear out, in-place on node data ----
// 64-node tile in LDS (stride 132 -> only 2-way bank aliasing). 512 threads,
// 4 nodes x 4 hidden per thread. Weight reads from WT are fully coalesced.
__global__ __launch_bounds__(512) void mlp_kernel(
    float* __restrict__ data, const float* __restrict__ WT,
    const float* __restrict__ bs, int N)
{
    __shared__ float xa[64][132];

    const int tid = threadIdx.x;
    const int nb  = blockIdx.x * 64;
    const int hq  = tid & 31, h0 = hq * 4;
    const int nq  = tid >> 5, n0 = nq * 4;

    for (int i = tid; i < 64 * 32; i += 512) {
        int n = i >> 5, kq = i & 31;
        float4 v = make_float4(0.f, 0.f, 0.f, 0.f);
        if (nb + n < N) v = *(const float4*)(data + (size_t)(nb + n) * HID + kq * 4);
        *(float4*)(&xa[n][kq * 4]) = v;
    }
    __syncthreads();

    for (int l = 0; l < NLAYER; ++l) {
        const float* __restrict__ W = WT + ((size_t)l << 14);
        float acc[4][4];
        if (l < 3) {
            float b[4];
#pragma unroll
            for (int j = 0; j < 4; ++j) b[j] = bs[l * HID + h0 + j];
#pragma unroll
            for (int i = 0; i < 4; ++i)
#pragma unroll
                for (int j = 0; j < 4; ++j) acc[i][j] = b[j];
        } else {
#pragma unroll
            for (int i = 0; i < 4; ++i)
#pragma unroll
                for (int j = 0; j < 4; ++j) acc[i][j] = 0.f;
        }

        for (int k4 = 0; k4 < 32; ++k4) {
            float4 xv[4];
#pragma unroll
            for (int i = 0; i < 4; ++i) xv[i] = *(const float4*)(&xa[n0 + i][k4 * 4]);
            float4 wr[4];   // rows k = 4*k4+kk of WT, cols h0..h0+3 (coalesced)
#pragma unroll
            for (int kk = 0; kk < 4; ++kk)
                wr[kk] = *(const float4*)(W + (size_t)(k4 * 4 + kk) * HID + h0);
#pragma unroll
            for (int i = 0; i < 4; ++i) {
                acc[i][0] += xv[i].x * wr[0].x + xv[i].y * wr[1].x + xv[i].z * wr[2].x + xv[i].w * wr[3].x;
                acc[i][1] += xv[i].x * wr[0].y + xv[i].y * wr[1].y + xv[i].z * wr[2].y + xv[i].w * wr[3].y;
                acc[i][2] += xv[i].x * wr[0].z + xv[i].y * wr[1].z + xv[i].z * wr[2].z + xv[i].w * wr[3].z;
                acc[i][3] += xv[i].x * wr[0].w + xv[i].y * wr[1].w + xv[i].z * wr[2].w + xv[i].w * wr[3].w;
            }
        }
        __syncthreads();

        if (l < 3) {
#pragma unroll
            for (int i = 0; i < 4; ++i) {
                float4 y;
                y.x = acc[i][0] / (1.f + __expf(-acc[i][0]));
                y.y = acc[i][1] / (1.f + __expf(-acc[i][1]));
                y.z = acc[i][2] / (1.f + __expf(-acc[i][2]));
                y.w = acc[i][3] / (1.f + __expf(-acc[i][3]));
                *(float4*)(&xa[n0 + i][h0]) = y;
            }
            __syncthreads();
        } else {
#pragma unroll
            for (int i = 0; i < 4; ++i) {
                if (nb + n0 + i < N) {
                    float4 y = make_float4(acc[i][0], acc[i][1], acc[i][2], acc[i][3]);
                    *(float4*)(data + (size_t)(nb + n0 + i) * HID + h0) = y;
                }
            }
        }
    }
}

extern "C" void kernel_launch(void* const* d_in, const int* in_sizes, int n_in,
                              void* d_out, int out_size, void* d_ws, size_t ws_size,
                              hipStream_t stream) {
    const float* dist = (const float*)d_in[0];
    const float* msg  = (const float*)d_in[1];
    const int*   eidx = (const int*)d_in[2];
    const float* Wd   = (const float*)d_in[4];
    const float* Ws   = (const float*)d_in[5];
    const float* bs   = (const float*)d_in[6];
    const float* Wout = (const float*)d_in[7];
    float* out = (float*)d_out;

    const int E = in_sizes[1] / HID;
    const int N = out_size / HID;

    // ws layout (all 4-byte elems; WT offset rounded to 16B)
    int*   hist   = (int*)d_ws;            // [N]
    int*   offs   = hist + N;              // [N]
    int*   curs   = offs + N;              // [N]
    int*   sorted = curs + N;              // [E]
    size_t wt_off = ((size_t)(3 * N + E) + 3) & ~(size_t)3;
    float* WT     = (float*)d_ws + wt_off; // [4*128*128]

    hipMemsetAsync(hist, 0, (size_t)N * sizeof(int), stream);

    hist_kernel   <<<(E + 255) / 256, 256, 0, stream>>>(eidx, hist, E);
    scan_kernel   <<<1, 1024, 0, stream>>>(hist, offs, curs, N);
    scatter_kernel<<<(E + 255) / 256, 256, 0, stream>>>(eidx, curs, sorted, E);
    transpose_kernel<<<(NLAYER * HID * HID + 255) / 256, 256, 0, stream>>>(Ws, Wout, WT);
    gather_kernel <<<(N + 3) / 4, 256, 0, stream>>>(dist, msg, Wd, sorted, offs, hist, out, N);
    mlp_kernel    <<<(N + 63) / 64, 512, 0, stream>>>(out, WT, bs, N);
}

// Round 3
// 368.786 us; speedup vs baseline: 2.1028x; 1.2275x over previous
//
#include <hip/hip_runtime.h>

#define HID 128
#define NR  16
#define NLAYER 4   // 3 hidden layers + output layer (transposed together)

__device__ __forceinline__ float dot4f(float4 a, float4 b) {
    return a.x * b.x + a.y * b.y + a.z * b.z + a.w * b.w;
}

// ---- K1: histogram of target indices ----
__global__ void hist_kernel(const int* __restrict__ eidx, int* __restrict__ hist, int E) {
    int e = blockIdx.x * blockDim.x + threadIdx.x;
    if (e < E) atomicAdd(&hist[eidx[E + e]], 1);
}

// ---- K2: single-block exclusive scan over N bins -> offs, curs ----
__global__ __launch_bounds__(1024) void scan_kernel(const int* __restrict__ hist,
                                                    int* __restrict__ offs,
                                                    int* __restrict__ curs, int N) {
    __shared__ int part[1024];
    const int tid = threadIdx.x;
    const int per = (N + 1023) >> 10;
    const int base = tid * per;
    int s = 0;
    for (int i = 0; i < per; ++i) {
        int idx = base + i;
        if (idx < N) s += hist[idx];
    }
    part[tid] = s;
    __syncthreads();
    for (int off = 1; off < 1024; off <<= 1) {
        int v = part[tid];
        int add = (tid >= off) ? part[tid - off] : 0;
        __syncthreads();
        part[tid] = v + add;
        __syncthreads();
    }
    int run = (tid > 0) ? part[tid - 1] : 0;
    for (int i = 0; i < per; ++i) {
        int idx = base + i;
        if (idx < N) {
            offs[idx] = run;
            curs[idx] = run;
            run += hist[idx];
        }
    }
}

// ---- K3: scatter edge ids into per-node contiguous segments ----
__global__ void scatter_kernel(const int* __restrict__ eidx, int* __restrict__ curs,
                               int* __restrict__ sorted, int E) {
    int e = blockIdx.x * blockDim.x + threadIdx.x;
    if (e < E) {
        int t = eidx[E + e];
        int pos = atomicAdd(&curs[t], 1);
        sorted[pos] = e;
    }
}

// ---- K4: transpose weights: WT[l][k][h] = W_l[h][k] (layer 3 = Wout) ----
__global__ void transpose_kernel(const float* __restrict__ Ws, const float* __restrict__ Wout,
                                 float* __restrict__ WT) {
    int i = blockIdx.x * blockDim.x + threadIdx.x;
    if (i >= NLAYER * HID * HID) return;
    int l = i >> 14;
    int rem = i & 16383;
    int h = rem >> 7, k = rem & 127;
    const float* src = (l < 3) ? (Ws + ((size_t)l << 14)) : Wout;
    WT[((size_t)l << 14) + (size_t)k * HID + h] = src[(size_t)h * HID + k];
}

// ---- K5: gather-reduce, 4-way edge-unrolled for memory-level parallelism ----
__global__ __launch_bounds__(256) void gather_kernel(
    const float* __restrict__ dist, const float* __restrict__ msg,
    const float* __restrict__ Wd, const int* __restrict__ sorted,
    const int* __restrict__ offs, const int* __restrict__ hist,
    float* __restrict__ node_emb, int N)
{
    const int tid  = threadIdx.x;
    const int lane = tid & 63;
    const int node = blockIdx.x * 4 + (tid >> 6);
    if (node >= N) return;

    float4 wd0[4], wd1[4];
#pragma unroll
    for (int q = 0; q < 4; ++q) {
        wd0[q] = *(const float4*)(Wd + (size_t)(2 * lane)     * NR + q * 4);
        wd1[q] = *(const float4*)(Wd + (size_t)(2 * lane + 1) * NR + q * 4);
    }

    const int start = offs[node];
    const int deg   = hist[node];
    float a0 = 0.f, a1 = 0.f;

    int i = 0;
    for (; i + 4 <= deg; i += 4) {
        int e0 = sorted[start + i + 0];
        int e1 = sorted[start + i + 1];
        int e2 = sorted[start + i + 2];
        int e3 = sorted[start + i + 3];
        float2 m0 = *(const float2*)(msg + (size_t)e0 * HID + 2 * lane);
        float2 m1 = *(const float2*)(msg + (size_t)e1 * HID + 2 * lane);
        float2 m2 = *(const float2*)(msg + (size_t)e2 * HID + 2 * lane);
        float2 m3 = *(const float2*)(msg + (size_t)e3 * HID + 2 * lane);
        const float4* p0 = (const float4*)(dist + (size_t)e0 * NR);
        const float4* p1 = (const float4*)(dist + (size_t)e1 * NR);
        const float4* p2 = (const float4*)(dist + (size_t)e2 * NR);
        const float4* p3 = (const float4*)(dist + (size_t)e3 * NR);
        float4 A0 = p0[0], A1 = p0[1], A2 = p0[2], A3 = p0[3];
        float4 B0 = p1[0], B1 = p1[1], B2 = p1[2], B3 = p1[3];
        float4 C0 = p2[0], C1 = p2[1], C2 = p2[2], C3 = p2[3];
        float4 D0 = p3[0], D1 = p3[1], D2 = p3[2], D3 = p3[3];

        float g;
        g = dot4f(A0, wd0[0]) + dot4f(A1, wd0[1]) + dot4f(A2, wd0[2]) + dot4f(A3, wd0[3]);
        a0 += g * m0.x;
        g = dot4f(A0, wd1[0]) + dot4f(A1, wd1[1]) + dot4f(A2, wd1[2]) + dot4f(A3, wd1[3]);
        a1 += g * m0.y;
        g = dot4f(B0, wd0[0]) + dot4f(B1, wd0[1]) + dot4f(B2, wd0[2]) + dot4f(B3, wd0[3]);
        a0 += g * m1.x;
        g = dot4f(B0, wd1[0]) + dot4f(B1, wd1[1]) + dot4f(B2, wd1[2]) + dot4f(B3, wd1[3]);
        a1 += g * m1.y;
        g = dot4f(C0, wd0[0]) + dot4f(C1, wd0[1]) + dot4f(C2, wd0[2]) + dot4f(C3, wd0[3]);
        a0 += g * m2.x;
        g = dot4f(C0, wd1[0]) + dot4f(C1, wd1[1]) + dot4f(C2, wd1[2]) + dot4f(C3, wd1[3]);
        a1 += g * m2.y;
        g = dot4f(D0, wd0[0]) + dot4f(D1, wd0[1]) + dot4f(D2, wd0[2]) + dot4f(D3, wd0[3]);
        a0 += g * m3.x;
        g = dot4f(D0, wd1[0]) + dot4f(D1, wd1[1]) + dot4f(D2, wd1[2]) + dot4f(D3, wd1[3]);
        a1 += g * m3.y;
    }
    for (; i < deg; ++i) {
        int e = sorted[start + i];
        const float4* dr = (const float4*)(dist + (size_t)e * NR);
        float4 d0 = dr[0], d1 = dr[1], d2 = dr[2], d3 = dr[3];
        float2 m  = *(const float2*)(msg + (size_t)e * HID + 2 * lane);
        float g0 = dot4f(d0, wd0[0]) + dot4f(d1, wd0[1]) +
                   dot4f(d2, wd0[2]) + dot4f(d3, wd0[3]);
        float g1 = dot4f(d0, wd1[0]) + dot4f(d1, wd1[1]) +
                   dot4f(d2, wd1[2]) + dot4f(d3, wd1[3]);
        a0 += g0 * m.x;
        a1 += g1 * m.y;
    }
    *(float2*)(node_emb + (size_t)node * HID + 2 * lane) = make_float2(a0, a1);
}

// ---- K6: fused 3x(Linear+SiLU) + Linear out, in-place on node data ----
__global__ __launch_bounds__(512) void mlp_kernel(
    float* __restrict__ data, const float* __restrict__ WT,
    const float* __restrict__ bs, int N)
{
    __shared__ float xa[64][132];

    const int tid = threadIdx.x;
    const int nb  = blockIdx.x * 64;
    const int hq  = tid & 31, h0 = hq * 4;
    const int nq  = tid >> 5, n0 = nq * 4;

    for (int i = tid; i < 64 * 32; i += 512) {
        int n = i >> 5, kq = i & 31;
        float4 v = make_float4(0.f, 0.f, 0.f, 0.f);
        if (nb + n < N) v = *(const float4*)(data + (size_t)(nb + n) * HID + kq * 4);
        *(float4*)(&xa[n][kq * 4]) = v;
    }
    __syncthreads();

    for (int l = 0; l < NLAYER; ++l) {
        const float* __restrict__ W = WT + ((size_t)l << 14);
        float acc[4][4];
        if (l < 3) {
            float b[4];
#pragma unroll
            for (int j = 0; j < 4; ++j) b[j] = bs[l * HID + h0 + j];
#pragma unroll
            for (int i = 0; i < 4; ++i)
#pragma unroll
                for (int j = 0; j < 4; ++j) acc[i][j] = b[j];
        } else {
#pragma unroll
            for (int i = 0; i < 4; ++i)
#pragma unroll
                for (int j = 0; j < 4; ++j) acc[i][j] = 0.f;
        }

        for (int k4 = 0; k4 < 32; ++k4) {
            float4 xv[4];
#pragma unroll
            for (int i = 0; i < 4; ++i) xv[i] = *(const float4*)(&xa[n0 + i][k4 * 4]);
            float4 wr[4];
#pragma unroll
            for (int kk = 0; kk < 4; ++kk)
                wr[kk] = *(const float4*)(W + (size_t)(k4 * 4 + kk) * HID + h0);
#pragma unroll
            for (int i = 0; i < 4; ++i) {
                acc[i][0] += xv[i].x * wr[0].x + xv[i].y * wr[1].x + xv[i].z * wr[2].x + xv[i].w * wr[3].x;
                acc[i][1] += xv[i].x * wr[0].y + xv[i].y * wr[1].y + xv[i].z * wr[2].y + xv[i].w * wr[3].y;
                acc[i][2] += xv[i].x * wr[0].z + xv[i].y * wr[1].z + xv[i].z * wr[2].z + xv[i].w * wr[3].z;
                acc[i][3] += xv[i].x * wr[0].w + xv[i].y * wr[1].w + xv[i].z * wr[2].w + xv[i].w * wr[3].w;
            }
        }
        __syncthreads();

        if (l < 3) {
#pragma unroll
            for (int i = 0; i < 4; ++i) {
                float4 y;
                y.x = acc[i][0] / (1.f + __expf(-acc[i][0]));
                y.y = acc[i][1] / (1.f + __expf(-acc[i][1]));
                y.z = acc[i][2] / (1.f + __expf(-acc[i][2]));
                y.w = acc[i][3] / (1.f + __expf(-acc[i][3]));
                *(float4*)(&xa[n0 + i][h0]) = y;
            }
            __syncthreads();
        } else {
#pragma unroll
            for (int i = 0; i < 4; ++i) {
                if (nb + n0 + i < N) {
                    float4 y = make_float4(acc[i][0], acc[i][1], acc[i][2], acc[i][3]);
                    *(float4*)(data + (size_t)(nb + n0 + i) * HID + h0) = y;
                }
            }
        }
    }
}

extern "C" void kernel_launch(void* const* d_in, const int* in_sizes, int n_in,
                              void* d_out, int out_size, void* d_ws, size_t ws_size,
                              hipStream_t stream) {
    const float* dist = (const float*)d_in[0];
    const float* msg  = (const float*)d_in[1];
    const int*   eidx = (const int*)d_in[2];
    const float* Wd   = (const float*)d_in[4];
    const float* Ws   = (const float*)d_in[5];
    const float* bs   = (const float*)d_in[6];
    const float* Wout = (const float*)d_in[7];
    float* out = (float*)d_out;

    const int E = in_sizes[1] / HID;
    const int N = out_size / HID;

    int*   hist   = (int*)d_ws;            // [N]
    int*   offs   = hist + N;              // [N]
    int*   curs   = offs + N;              // [N]
    int*   sorted = curs + N;              // [E]
    size_t wt_off = ((size_t)(3 * N + E) + 3) & ~(size_t)3;
    float* WT     = (float*)d_ws + wt_off; // [4*128*128]

    hipMemsetAsync(hist, 0, (size_t)N * sizeof(int), stream);

    hist_kernel   <<<(E + 255) / 256, 256, 0, stream>>>(eidx, hist, E);
    scan_kernel   <<<1, 1024, 0, stream>>>(hist, offs, curs, N);
    scatter_kernel<<<(E + 255) / 256, 256, 0, stream>>>(eidx, curs, sorted, E);
    transpose_kernel<<<(NLAYER * HID * HID + 255) / 256, 256, 0, stream>>>(Ws, Wout, WT);
    gather_kernel <<<(N + 3) / 4, 256, 0, stream>>>(dist, msg, Wd, sorted, offs, hist, out, N);
    mlp_kernel    <<<(N + 63) / 64, 512, 0, stream>>>(out, WT, bs, N);
}

// Round 4
// 304.570 us; speedup vs baseline: 2.5462x; 1.2108x over previous
//
#include <hip/hip_runtime.h>

#define HID 128
#define NR  16
#define NLAYER 4   // 3 hidden layers + output layer (transposed together)
#define CHUNK 16   // sorted edges per wave

__device__ __forceinline__ float dot4f(float4 a, float4 b) {
    return a.x * b.x + a.y * b.y + a.z * b.z + a.w * b.w;
}

// ---- K1: histogram of target indices (4 edges/thread, int4 loads) ----
__global__ void hist_kernel(const int* __restrict__ eidx, int* __restrict__ hist, int E) {
    int i = (blockIdx.x * blockDim.x + threadIdx.x) * 4;
    if (i + 4 <= E) {
        int4 v = *(const int4*)(eidx + E + i);
        atomicAdd(&hist[v.x], 1);
        atomicAdd(&hist[v.y], 1);
        atomicAdd(&hist[v.z], 1);
        atomicAdd(&hist[v.w], 1);
    } else {
        for (; i < E; ++i) atomicAdd(&hist[eidx[E + i]], 1);
    }
}

// ---- K2: single-block exclusive scan over N bins -> curs ----
__global__ __launch_bounds__(1024) void scan_kernel(const int* __restrict__ hist,
                                                    int* __restrict__ curs, int N) {
    __shared__ int part[1024];
    const int tid = threadIdx.x;
    const int per = (N + 1023) >> 10;
    const int base = tid * per;
    int s = 0;
    for (int i = 0; i < per; ++i) {
        int idx = base + i;
        if (idx < N) s += hist[idx];
    }
    part[tid] = s;
    __syncthreads();
    for (int off = 1; off < 1024; off <<= 1) {
        int v = part[tid];
        int add = (tid >= off) ? part[tid - off] : 0;
        __syncthreads();
        part[tid] = v + add;
        __syncthreads();
    }
    int run = (tid > 0) ? part[tid - 1] : 0;
    for (int i = 0; i < per; ++i) {
        int idx = base + i;
        if (idx < N) {
            curs[idx] = run;
            run += hist[idx];
        }
    }
}

// ---- K3: scatter edge ids + targets into sorted segments (4 edges/thread) ----
__global__ void scatter_kernel(const int* __restrict__ eidx, int* __restrict__ curs,
                               int* __restrict__ sorted, int* __restrict__ stgt, int E) {
    int i = (blockIdx.x * blockDim.x + threadIdx.x) * 4;
    if (i + 4 <= E) {
        int4 v = *(const int4*)(eidx + E + i);
        int p;
        p = atomicAdd(&curs[v.x], 1); sorted[p] = i + 0; stgt[p] = v.x;
        p = atomicAdd(&curs[v.y], 1); sorted[p] = i + 1; stgt[p] = v.y;
        p = atomicAdd(&curs[v.z], 1); sorted[p] = i + 2; stgt[p] = v.z;
        p = atomicAdd(&curs[v.w], 1); sorted[p] = i + 3; stgt[p] = v.w;
    } else {
        for (; i < E; ++i) {
            int t = eidx[E + i];
            int p = atomicAdd(&curs[t], 1);
            sorted[p] = i; stgt[p] = t;
        }
    }
}

// ---- K4: transpose weights: WT[l][k][h] = W_l[h][k] (layer 3 = Wout) ----
__global__ void transpose_kernel(const float* __restrict__ Ws, const float* __restrict__ Wout,
                                 float* __restrict__ WT) {
    int i = blockIdx.x * blockDim.x + threadIdx.x;
    if (i >= NLAYER * HID * HID) return;
    int l = i >> 14;
    int rem = i & 16383;
    int h = rem >> 7, k = rem & 127;
    const float* src = (l < 3) ? (Ws + ((size_t)l << 14)) : Wout;
    WT[((size_t)l << 14) + (size_t)k * HID + h] = src[(size_t)h * HID + k];
}

// ---- K5: edge-parallel gather over sorted edges, segmented atomic flush ----
// Wave owns 16 consecutive sorted edges. All index/msg/dist loads for the
// chunk are issued in one latency window: ids+tgts via 4 uniform int4 loads,
// dist rows via 4 coalesced lane-spread loads staged through per-wave LDS,
// msg via 16 coalesced float2 loads. Lane covers channels 2*lane, 2*lane+1.
// Targets are wave-uniform; flush partial sums at segment boundaries with
// 2 atomic adds per lane.
__global__ __launch_bounds__(256, 4) void gather_kernel(
    const float* __restrict__ dist, const float* __restrict__ msg,
    const float* __restrict__ Wd, const int* __restrict__ sorted,
    const int* __restrict__ stgt, float* __restrict__ node_emb, int E)
{
    __shared__ float sdist[4][CHUNK * NR];   // 1 KB per wave, private region

    const int tid  = threadIdx.x;
    const int lane = tid & 63;
    const int wv   = tid >> 6;
    const long base = ((long)blockIdx.x * 4 + wv) * CHUNK;
    if (base >= E) return;
    const int cnt = (E - base < CHUNK) ? (int)(E - base) : CHUNK;

    // Wd rows for channels 2*lane, 2*lane+1 (16 floats each) in registers
    float4 wd0[4], wd1[4];
#pragma unroll
    for (int q = 0; q < 4; ++q) {
        wd0[q] = *(const float4*)(Wd + (size_t)(2 * lane)     * NR + q * 4);
        wd1[q] = *(const float4*)(Wd + (size_t)(2 * lane + 1) * NR + q * 4);
    }

    int ids[CHUNK], tg[CHUNK];
    if (cnt == CHUNK) {
#pragma unroll
        for (int q = 0; q < CHUNK / 4; ++q) {
            int4 a = *(const int4*)(sorted + base + q * 4);
            int4 b = *(const int4*)(stgt   + base + q * 4);
            ids[q*4+0] = a.x; ids[q*4+1] = a.y; ids[q*4+2] = a.z; ids[q*4+3] = a.w;
            tg [q*4+0] = b.x; tg [q*4+1] = b.y; tg [q*4+2] = b.z; tg [q*4+3] = b.w;
        }
    } else {
#pragma unroll
        for (int i = 0; i < CHUNK; ++i) {
            ids[i] = (i < cnt) ? sorted[base + i] : 0;
            tg[i]  = (i < cnt) ? stgt[base + i]  : -1;
        }
    }

    // dist rows, coalesced: group g loads rows of edges g*4..g*4+3;
    // lane -> (row = lane>>4, elem = lane&15). 4 instructions, 4 VGPRs.
    float dv[CHUNK / 4];
#pragma unroll
    for (int g = 0; g < CHUNK / 4; ++g) {
        int e = ids[g * 4 + (lane >> 4)];
        dv[g] = dist[(size_t)e * NR + (lane & 15)];
    }

    // all msg loads issued together (8 KB per wave in flight)
    float2 m[CHUNK];
#pragma unroll
    for (int i = 0; i < CHUNK; ++i)
        m[i] = *(const float2*)(msg + (size_t)ids[i] * HID + 2 * lane);

    // stage dist rows into this wave's LDS region (no barrier: wave-private)
    float* sd = sdist[wv];
#pragma unroll
    for (int g = 0; g < CHUNK / 4; ++g)
        sd[g * 64 + lane] = dv[g];

    float a0 = 0.f, a1 = 0.f;
#pragma unroll
    for (int i = 0; i < CHUNK; ++i) {
        if (i < cnt) {
            const float4* dr = (const float4*)(sd + i * NR);   // uniform broadcast
            float4 d0 = dr[0], d1 = dr[1], d2 = dr[2], d3 = dr[3];
            float g0 = dot4f(d0, wd0[0]) + dot4f(d1, wd0[1]) +
                       dot4f(d2, wd0[2]) + dot4f(d3, wd0[3]);
            float g1 = dot4f(d0, wd1[0]) + dot4f(d1, wd1[1]) +
                       dot4f(d2, wd1[2]) + dot4f(d3, wd1[3]);
            a0 += g0 * m[i].x;
            a1 += g1 * m[i].y;
            bool fl = (i == cnt - 1) || (tg[i + 1] != tg[i]);
            if (fl) {
                float* dst = node_emb + (size_t)tg[i] * HID + 2 * lane;
                unsafeAtomicAdd(dst,     a0);
                unsafeAtomicAdd(dst + 1, a1);
                a0 = 0.f; a1 = 0.f;
            }
        }
    }
}

// ---- K6: fused 3x(Linear+SiLU) + Linear out, in-place on node data ----
__global__ __launch_bounds__(512) void mlp_kernel(
    float* __restrict__ data, const float* __restrict__ WT,
    const float* __restrict__ bs, int N)
{
    __shared__ float xa[64][132];

    const int tid = threadIdx.x;
    const int nb  = blockIdx.x * 64;
    const int hq  = tid & 31, h0 = hq * 4;
    const int nq  = tid >> 5, n0 = nq * 4;

    for (int i = tid; i < 64 * 32; i += 512) {
        int n = i >> 5, kq = i & 31;
        float4 v = make_float4(0.f, 0.f, 0.f, 0.f);
        if (nb + n < N) v = *(const float4*)(data + (size_t)(nb + n) * HID + kq * 4);
        *(float4*)(&xa[n][kq * 4]) = v;
    }
    __syncthreads();

    for (int l = 0; l < NLAYER; ++l) {
        const float* __restrict__ W = WT + ((size_t)l << 14);
        float acc[4][4];
        if (l < 3) {
            float b[4];
#pragma unroll
            for (int j = 0; j < 4; ++j) b[j] = bs[l * HID + h0 + j];
#pragma unroll
            for (int i = 0; i < 4; ++i)
#pragma unroll
                for (int j = 0; j < 4; ++j) acc[i][j] = b[j];
        } else {
#pragma unroll
            for (int i = 0; i < 4; ++i)
#pragma unroll
                for (int j = 0; j < 4; ++j) acc[i][j] = 0.f;
        }

        for (int k4 = 0; k4 < 32; ++k4) {
            float4 xv[4];
#pragma unroll
            for (int i = 0; i < 4; ++i) xv[i] = *(const float4*)(&xa[n0 + i][k4 * 4]);
            float4 wr[4];
#pragma unroll
            for (int kk = 0; kk < 4; ++kk)
                wr[kk] = *(const float4*)(W + (size_t)(k4 * 4 + kk) * HID + h0);
#pragma unroll
            for (int i = 0; i < 4; ++i) {
                acc[i][0] += xv[i].x * wr[0].x + xv[i].y * wr[1].x + xv[i].z * wr[2].x + xv[i].w * wr[3].x;
                acc[i][1] += xv[i].x * wr[0].y + xv[i].y * wr[1].y + xv[i].z * wr[2].y + xv[i].w * wr[3].y;
                acc[i][2] += xv[i].x * wr[0].z + xv[i].y * wr[1].z + xv[i].z * wr[2].z + xv[i].w * wr[3].z;
                acc[i][3] += xv[i].x * wr[0].w + xv[i].y * wr[1].w + xv[i].z * wr[2].w + xv[i].w * wr[3].w;
            }
        }
        __syncthreads();

        if (l < 3) {
#pragma unroll
            for (int i = 0; i < 4; ++i) {
                float4 y;
                y.x = acc[i][0] / (1.f + __expf(-acc[i][0]));
                y.y = acc[i][1] / (1.f + __expf(-acc[i][1]));
                y.z = acc[i][2] / (1.f + __expf(-acc[i][2]));
                y.w = acc[i][3] / (1.f + __expf(-acc[i][3]));
                *(float4*)(&xa[n0 + i][h0]) = y;
            }
            __syncthreads();
        } else {
#pragma unroll
            for (int i = 0; i < 4; ++i) {
                if (nb + n0 + i < N) {
                    float4 y = make_float4(acc[i][0], acc[i][1], acc[i][2], acc[i][3]);
                    *(float4*)(data + (size_t)(nb + n0 + i) * HID + h0) = y;
                }
            }
        }
    }
}

extern "C" void kernel_launch(void* const* d_in, const int* in_sizes, int n_in,
                              void* d_out, int out_size, void* d_ws, size_t ws_size,
                              hipStream_t stream) {
    const float* dist = (const float*)d_in[0];
    const float* msg  = (const float*)d_in[1];
    const int*   eidx = (const int*)d_in[2];
    const float* Wd   = (const float*)d_in[4];
    const float* Ws   = (const float*)d_in[5];
    const float* bs   = (const float*)d_in[6];
    const float* Wout = (const float*)d_in[7];
    float* out = (float*)d_out;

    const int E = in_sizes[1] / HID;
    const int N = out_size / HID;

    // ws layout (4-byte elems)
    int*   hist   = (int*)d_ws;            // [N]
    int*   curs   = hist + N;              // [N]
    int*   sorted = curs + N;              // [E]
    int*   stgt   = sorted + E;            // [E]
    size_t wt_off = ((size_t)(2 * N + 2 * E) + 3) & ~(size_t)3;
    float* WT     = (float*)d_ws + wt_off; // [4*128*128]

    hipMemsetAsync(hist, 0, (size_t)N * sizeof(int), stream);
    // gather accumulates atomically into d_out: zero it every launch
    hipMemsetAsync(out, 0, (size_t)N * HID * sizeof(float), stream);

    const int qE = (E + 3) / 4;
    hist_kernel   <<<(qE + 255) / 256, 256, 0, stream>>>(eidx, hist, E);
    scan_kernel   <<<1, 1024, 0, stream>>>(hist, curs, N);
    scatter_kernel<<<(qE + 255) / 256, 256, 0, stream>>>(eidx, curs, sorted, stgt, E);
    transpose_kernel<<<(NLAYER * HID * HID + 255) / 256, 256, 0, stream>>>(Ws, Wout, WT);

    const long waves = ((long)E + CHUNK - 1) / CHUNK;
    gather_kernel <<<(int)((waves + 3) / 4), 256, 0, stream>>>(dist, msg, Wd, sorted, stgt, out, E);
    mlp_kernel    <<<(N + 63) / 64, 512, 0, stream>>>(out, WT, bs, N);
}

// Round 5
// 290.767 us; speedup vs baseline: 2.6671x; 1.0475x over previous
//
#include <hip/hip_runtime.h>

#define HID 128
#define NR  16
#define NLAYER 4   // 3 hidden layers + output layer (transposed together)
#define CHUNK 16   // sorted edges per wave
#define MAXN_LDS 20480

__device__ __forceinline__ float dot4f(float4 a, float4 b) {
    return a.x * b.x + a.y * b.y + a.z * b.z + a.w * b.w;
}

// ---- K1: histogram of target indices (4 edges/thread, int4 loads) ----
__global__ void hist_kernel(const int* __restrict__ eidx, int* __restrict__ hist, int E) {
    int i = (blockIdx.x * blockDim.x + threadIdx.x) * 4;
    if (i + 4 <= E) {
        int4 v = *(const int4*)(eidx + E + i);
        atomicAdd(&hist[v.x], 1);
        atomicAdd(&hist[v.y], 1);
        atomicAdd(&hist[v.z], 1);
        atomicAdd(&hist[v.w], 1);
    } else {
        for (; i < E; ++i) atomicAdd(&hist[eidx[E + i]], 1);
    }
}

// ---- K2: block 0 = exclusive scan (LDS-staged); blocks >=1 = weight transpose ----
__global__ __launch_bounds__(1024) void prep_kernel(const int* __restrict__ hist,
                                                    int* __restrict__ curs, int N,
                                                    const float* __restrict__ Ws,
                                                    const float* __restrict__ Wout,
                                                    float* __restrict__ WT) {
    const int tid = threadIdx.x;
    if (blockIdx.x > 0) {
        // transpose: WT[l][k][h] = W_l[h][k] (layer 3 = Wout)
        int idx = (blockIdx.x - 1) * 1024 + tid;
        if (idx < NLAYER * HID * HID) {
            int l = idx >> 14;
            int rem = idx & 16383;
            int h = rem >> 7, k = rem & 127;
            const float* src = (l < 3) ? (Ws + ((size_t)l << 14)) : Wout;
            WT[((size_t)l << 14) + (size_t)k * HID + h] = src[(size_t)h * HID + k];
        }
        return;
    }
    __shared__ int sh[MAXN_LDS];
    __shared__ int part[1024];
    const bool use_lds = (N <= MAXN_LDS);
    if (use_lds) {
        for (int i = tid; i < N; i += 1024) sh[i] = hist[i];   // coalesced
        __syncthreads();
    }
    const int per = (N + 1023) >> 10;
    const int base = tid * per;
    int s = 0;
    for (int i = 0; i < per; ++i) {
        int idx = base + i;
        if (idx < N) s += use_lds ? sh[idx] : hist[idx];
    }
    part[tid] = s;
    __syncthreads();
    for (int off = 1; off < 1024; off <<= 1) {
        int v = part[tid];
        int add = (tid >= off) ? part[tid - off] : 0;
        __syncthreads();
        part[tid] = v + add;
        __syncthreads();
    }
    int run = (tid > 0) ? part[tid - 1] : 0;
    for (int i = 0; i < per; ++i) {
        int idx = base + i;
        if (idx < N) {
            curs[idx] = run;
            run += use_lds ? sh[idx] : hist[idx];
        }
    }
}

// ---- K3: scatter {edge,target} pairs into sorted segments (4 edges/thread) ----
__global__ void scatter_kernel(const int* __restrict__ eidx, int* __restrict__ curs,
                               int2* __restrict__ pairs, int E) {
    int i = (blockIdx.x * blockDim.x + threadIdx.x) * 4;
    if (i + 4 <= E) {
        int4 v = *(const int4*)(eidx + E + i);
        int p;
        p = atomicAdd(&curs[v.x], 1); pairs[p] = make_int2(i + 0, v.x);
        p = atomicAdd(&curs[v.y], 1); pairs[p] = make_int2(i + 1, v.y);
        p = atomicAdd(&curs[v.z], 1); pairs[p] = make_int2(i + 2, v.z);
        p = atomicAdd(&curs[v.w], 1); pairs[p] = make_int2(i + 3, v.w);
    } else {
        for (; i < E; ++i) {
            int t = eidx[E + i];
            int p = atomicAdd(&curs[t], 1);
            pairs[p] = make_int2(i, t);
        }
    }
}

// ---- K4: edge-parallel gather over sorted edges, segmented atomic flush ----
// Wave owns 16 consecutive sorted edges. ids+targets via 8 uniform int4 loads;
// dist rows staged coalescedly through wave-private LDS; msg via 16 coalesced
// float2 loads. Gate dot is split across lane pairs: even lane handles
// k=[0,8), odd lane k=[8,16), each computes 4 channel-partials for the pair's
// 4 channels; one shfl_xor(.,1) recombines. Halves LDS b128 reads vs full-row.
__global__ __launch_bounds__(256, 4) void gather_kernel(
    const float* __restrict__ dist, const float* __restrict__ msg,
    const float* __restrict__ Wd, const int2* __restrict__ pairs,
    float* __restrict__ node_emb, int E)
{
    __shared__ float sdist[4][CHUNK * NR];   // 1 KB per wave, private region

    const int tid  = threadIdx.x;
    const int lane = tid & 63;
    const int wv   = tid >> 6;
    const long base = ((long)blockIdx.x * 4 + wv) * CHUNK;
    if (base >= E) return;
    const int cnt = (E - base < CHUNK) ? (int)(E - base) : CHUNK;

    // Half-row Wd fragments for the lane pair's 4 channels:
    // base_ch = 4*(lane>>1), k-half = (lane&1)*8. 8 float4 = 32 VGPR.
    const int base_ch = (lane >> 1) << 2;
    const int kh      = (lane & 1) * 8;
    float4 wdh[4][2];
#pragma unroll
    for (int j = 0; j < 4; ++j) {
        wdh[j][0] = *(const float4*)(Wd + (size_t)(base_ch + j) * NR + kh);
        wdh[j][1] = *(const float4*)(Wd + (size_t)(base_ch + j) * NR + kh + 4);
    }

    int ids[CHUNK], tg[CHUNK];
    if (cnt == CHUNK) {
#pragma unroll
        for (int q = 0; q < CHUNK / 2; ++q) {   // int4 = 2 {edge,tgt} pairs
            int4 v = *(const int4*)(pairs + base + q * 2);
            ids[q*2+0] = v.x; tg[q*2+0] = v.y;
            ids[q*2+1] = v.z; tg[q*2+1] = v.w;
        }
    } else {
#pragma unroll
        for (int i = 0; i < CHUNK; ++i) {
            int2 v = (i < cnt) ? pairs[base + i] : make_int2(0, -1);
            ids[i] = v.x; tg[i] = v.y;
        }
    }

    // dist rows, coalesced: group g loads rows of edges g*4..g*4+3;
    // lane -> (row = lane>>4, elem = lane&15).
    float dv[CHUNK / 4];
#pragma unroll
    for (int g = 0; g < CHUNK / 4; ++g) {
        int e = ids[g * 4 + (lane >> 4)];
        dv[g] = dist[(size_t)e * NR + (lane & 15)];
    }

    // all msg loads issued together (8 KB per wave in flight)
    float2 m[CHUNK];
#pragma unroll
    for (int i = 0; i < CHUNK; ++i)
        m[i] = *(const float2*)(msg + (size_t)ids[i] * HID + 2 * lane);

    // stage dist rows into this wave's LDS region (wave-private, no barrier)
    float* sd = sdist[wv];
#pragma unroll
    for (int g = 0; g < CHUNK / 4; ++g)
        sd[g * 64 + lane] = dv[g];

    const bool odd = (lane & 1);
    float a0 = 0.f, a1 = 0.f;
#pragma unroll
    for (int i = 0; i < CHUNK; ++i) {
        if (i < cnt) {
            const float4* dr = (const float4*)(sd + i * NR + kh);  // half row
            float4 d0 = dr[0], d1 = dr[1];
            float p0 = dot4f(d0, wdh[0][0]) + dot4f(d1, wdh[0][1]);
            float p1 = dot4f(d0, wdh[1][0]) + dot4f(d1, wdh[1][1]);
            float p2 = dot4f(d0, wdh[2][0]) + dot4f(d1, wdh[2][1]);
            float p3 = dot4f(d0, wdh[3][0]) + dot4f(d1, wdh[3][1]);
            // exchange the partner's 2 channels' partials
            float s0 = odd ? p0 : p2;
            float s1 = odd ? p1 : p3;
            float r0 = __shfl_xor(s0, 1, 64);
            float r1 = __shfl_xor(s1, 1, 64);
            float g0 = (odd ? p2 : p0) + r0;
            float g1 = (odd ? p3 : p1) + r1;
            a0 += g0 * m[i].x;
            a1 += g1 * m[i].y;
            bool fl = (i == cnt - 1) || (tg[i + 1] != tg[i]);
            if (fl) {
                float* dst = node_emb + (size_t)tg[i] * HID + 2 * lane;
                unsafeAtomicAdd(dst,     a0);
                unsafeAtomicAdd(dst + 1, a1);
                a0 = 0.f; a1 = 0.f;
            }
        }
    }
}

// ---- K5: fused 3x(Linear+SiLU) + Linear out, in-place on node data ----
__global__ __launch_bounds__(512) void mlp_kernel(
    float* __restrict__ data, const float* __restrict__ WT,
    const float* __restrict__ bs, int N)
{
    __shared__ float xa[64][132];

    const int tid = threadIdx.x;
    const int nb  = blockIdx.x * 64;
    const int hq  = tid & 31, h0 = hq * 4;
    const int nq  = tid >> 5, n0 = nq * 4;

    for (int i = tid; i < 64 * 32; i += 512) {
        int n = i >> 5, kq = i & 31;
        float4 v = make_float4(0.f, 0.f, 0.f, 0.f);
        if (nb + n < N) v = *(const float4*)(data + (size_t)(nb + n) * HID + kq * 4);
        *(float4*)(&xa[n][kq * 4]) = v;
    }
    __syncthreads();

    for (int l = 0; l < NLAYER; ++l) {
        const float* __restrict__ W = WT + ((size_t)l << 14);
        float acc[4][4];
        if (l < 3) {
            float b[4];
#pragma unroll
            for (int j = 0; j < 4; ++j) b[j] = bs[l * HID + h0 + j];
#pragma unroll
            for (int i = 0; i < 4; ++i)
#pragma unroll
                for (int j = 0; j < 4; ++j) acc[i][j] = b[j];
        } else {
#pragma unroll
            for (int i = 0; i < 4; ++i)
#pragma unroll
                for (int j = 0; j < 4; ++j) acc[i][j] = 0.f;
        }

        for (int k4 = 0; k4 < 32; ++k4) {
            float4 xv[4];
#pragma unroll
            for (int i = 0; i < 4; ++i) xv[i] = *(const float4*)(&xa[n0 + i][k4 * 4]);
            float4 wr[4];
#pragma unroll
            for (int kk = 0; kk < 4; ++kk)
                wr[kk] = *(const float4*)(W + (size_t)(k4 * 4 + kk) * HID + h0);
#pragma unroll
            for (int i = 0; i < 4; ++i) {
                acc[i][0] += xv[i].x * wr[0].x + xv[i].y * wr[1].x + xv[i].z * wr[2].x + xv[i].w * wr[3].x;
                acc[i][1] += xv[i].x * wr[0].y + xv[i].y * wr[1].y + xv[i].z * wr[2].y + xv[i].w * wr[3].y;
                acc[i][2] += xv[i].x * wr[0].z + xv[i].y * wr[1].z + xv[i].z * wr[2].z + xv[i].w * wr[3].z;
                acc[i][3] += xv[i].x * wr[0].w + xv[i].y * wr[1].w + xv[i].z * wr[2].w + xv[i].w * wr[3].w;
            }
        }
        __syncthreads();

        if (l < 3) {
#pragma unroll
            for (int i = 0; i < 4; ++i) {
                float4 y;
                y.x = acc[i][0] / (1.f + __expf(-acc[i][0]));
                y.y = acc[i][1] / (1.f + __expf(-acc[i][1]));
                y.z = acc[i][2] / (1.f + __expf(-acc[i][2]));
                y.w = acc[i][3] / (1.f + __expf(-acc[i][3]));
                *(float4*)(&xa[n0 + i][h0]) = y;
            }
            __syncthreads();
        } else {
#pragma unroll
            for (int i = 0; i < 4; ++i) {
                if (nb + n0 + i < N) {
                    float4 y = make_float4(acc[i][0], acc[i][1], acc[i][2], acc[i][3]);
                    *(float4*)(data + (size_t)(nb + n0 + i) * HID + h0) = y;
                }
            }
        }
    }
}

extern "C" void kernel_launch(void* const* d_in, const int* in_sizes, int n_in,
                              void* d_out, int out_size, void* d_ws, size_t ws_size,
                              hipStream_t stream) {
    const float* dist = (const float*)d_in[0];
    const float* msg  = (const float*)d_in[1];
    const int*   eidx = (const int*)d_in[2];
    const float* Wd   = (const float*)d_in[4];
    const float* Ws   = (const float*)d_in[5];
    const float* bs   = (const float*)d_in[6];
    const float* Wout = (const float*)d_in[7];
    float* out = (float*)d_out;

    const int E = in_sizes[1] / HID;
    const int N = out_size / HID;

    // ws layout (4-byte elems; pairs needs 16 B alignment for int4 loads)
    int*   hist   = (int*)d_ws;                       // [N]
    int*   curs   = hist + N;                         // [N]
    size_t pr_off = ((size_t)(2 * N) + 3) & ~(size_t)3;
    int2*  pairs  = (int2*)((int*)d_ws + pr_off);     // [E] {edge,tgt}
    size_t wt_off = (pr_off + (size_t)2 * E + 3) & ~(size_t)3;
    float* WT     = (float*)d_ws + wt_off;            // [4*128*128]

    hipMemsetAsync(hist, 0, (size_t)N * sizeof(int), stream);
    // gather accumulates atomically into d_out: zero it every launch
    hipMemsetAsync(out, 0, (size_t)N * HID * sizeof(float), stream);

    const int qE = (E + 3) / 4;
    const int tblocks = (NLAYER * HID * HID + 1023) / 1024;
    hist_kernel   <<<(qE + 255) / 256, 256, 0, stream>>>(eidx, hist, E);
    prep_kernel   <<<1 + tblocks, 1024, 0, stream>>>(hist, curs, N, Ws, Wout, WT);
    scatter_kernel<<<(qE + 255) / 256, 256, 0, stream>>>(eidx, curs, pairs, E);

    const long waves = ((long)E + CHUNK - 1) / CHUNK;
    gather_kernel <<<(int)((waves + 3) / 4), 256, 0, stream>>>(dist, msg, Wd, pairs, out, E);
    mlp_kernel    <<<(N + 63) / 64, 512, 0, stream>>>(out, WT, bs, N);
}